// Round 2
// baseline (478.301 us; speedup 1.0000x reference)
//
#include <hip/hip_runtime.h>

#define Bn 16
#define Ln 128
#define Hn 256
#define Dn 256

// Output layout (flat fp32 concat, reference return order)
#define OFF_MASK   0          // (B,L,L) 262144
#define OFF_SMP    262144     // (B,L,L) 262144
#define OFF_ENT    524288     // (B,L,L) 262144
#define OFF_GRAPH  786432     // (L,L)   16384
#define OFF_LSE    802816     // scalar
#define OFF_EREG   802817     // (B,)    16

static __device__ __forceinline__ unsigned rotl32(unsigned x, int r) {
  return (x << r) | (x >> (32 - r));
}

// Threefry-2x32, 20 rounds, key = (0,1)  [jax.random.key(1)], partitionable
// random-bits path: counter = (hi=0, lo=flat_index), output = y0 ^ y1.
static __device__ __forceinline__ unsigned threefry_bits(unsigned c_hi, unsigned c_lo) {
  const unsigned ks0 = 0u, ks1 = 1u;
  const unsigned ks2 = 0u ^ 1u ^ 0x1BD11BDAu;
  unsigned x0 = c_hi + ks0;
  unsigned x1 = c_lo + ks1;
  x0 += x1; x1 = rotl32(x1, 13); x1 ^= x0;
  x0 += x1; x1 = rotl32(x1, 15); x1 ^= x0;
  x0 += x1; x1 = rotl32(x1, 26); x1 ^= x0;
  x0 += x1; x1 = rotl32(x1, 6);  x1 ^= x0;
  x0 += ks1; x1 += ks2 + 1u;
  x0 += x1; x1 = rotl32(x1, 17); x1 ^= x0;
  x0 += x1; x1 = rotl32(x1, 29); x1 ^= x0;
  x0 += x1; x1 = rotl32(x1, 16); x1 ^= x0;
  x0 += x1; x1 = rotl32(x1, 24); x1 ^= x0;
  x0 += ks2; x1 += ks0 + 2u;
  x0 += x1; x1 = rotl32(x1, 13); x1 ^= x0;
  x0 += x1; x1 = rotl32(x1, 15); x1 ^= x0;
  x0 += x1; x1 = rotl32(x1, 26); x1 ^= x0;
  x0 += x1; x1 = rotl32(x1, 6);  x1 ^= x0;
  x0 += ks0; x1 += ks1 + 3u;
  x0 += x1; x1 = rotl32(x1, 17); x1 ^= x0;
  x0 += x1; x1 = rotl32(x1, 29); x1 ^= x0;
  x0 += x1; x1 = rotl32(x1, 16); x1 ^= x0;
  x0 += x1; x1 = rotl32(x1, 24); x1 ^= x0;
  x0 += ks1; x1 += ks2 + 4u;
  x0 += x1; x1 = rotl32(x1, 13); x1 ^= x0;
  x0 += x1; x1 = rotl32(x1, 15); x1 ^= x0;
  x0 += x1; x1 = rotl32(x1, 26); x1 ^= x0;
  x0 += x1; x1 = rotl32(x1, 6);  x1 ^= x0;
  x0 += ks2; x1 += ks0 + 5u;
  return x0 ^ x1;
}

static __device__ __forceinline__ float softplus_f(float x) {
  // max(x,0) + log1p(exp(-|x|)); exact at |x|=1e8 (exp(-1e8)=0)
  return fmaxf(x, 0.0f) + log1pf(__expf(-fabsf(x)));
}

static __device__ __forceinline__ float fast_tanh(float x) {
  // tanh(x) = 2/(1+e^{-2x}) - 1; saturates correctly for |x| large
  float e = __expf(-2.0f * x);
  float r = __builtin_amdgcn_rcpf(1.0f + e);
  return fmaf(2.0f, r, -1.0f);
}

// fp32 projections, 4 rows per block (512 blocks = 2/CU), LDS-staged enc AND
// LDS-staged Wl/Wr (8 chunks of 32 h-rows, float4 reg-staging -> 128 VMEM
// instrs/thread instead of 512 scalar loads). Compute order per (row,d)
// output is the SAME h-ascending fma chain -> dl/dr bit-identical to R9.
// LDS = 68KB -> 2 blocks/CU, equal to the grid-limited occupancy (no loss).
__global__ void proj_kernel(const float* __restrict__ enc,
                            const float* __restrict__ Wl,
                            const float* __restrict__ Wr,
                            float* __restrict__ dl,
                            float* __restrict__ dr,
                            float* __restrict__ out,
                            double* __restrict__ ws_acc) {
  int gid = blockIdx.x * blockDim.x + threadIdx.x;
  if (gid < Ln * Ln) out[OFF_GRAPH + gid] = 0.0f;
  if (gid < 18) ws_acc[gid] = 0.0;

  int r0 = blockIdx.x * 4;     // 512 blocks x 4 rows = 2048 rows
  int d = threadIdx.x;         // 0..255
  __shared__ float encS[4][Hn];     // 4 KB
  __shared__ float WlS[32][Dn];     // 32 KB (one 32-h chunk)
  __shared__ float WrS[32][Dn];     // 32 KB
  ((float4*)encS)[d] = ((const float4*)(enc + (size_t)r0 * Hn))[d];

  float al[4] = {0.f, 0.f, 0.f, 0.f};
  float ar[4] = {0.f, 0.f, 0.f, 0.f};

  for (int c = 0; c < 8; ++c) {
    // protect WlS/WrS from previous chunk's readers (also orders encS @ c=0)
    __syncthreads();
    {
      const float4* wlg = (const float4*)(Wl + (size_t)c * 32 * Dn);
      const float4* wrg = (const float4*)(Wr + (size_t)c * 32 * Dn);
      float4 wl4[8], wr4[8];
#pragma unroll
      for (int s = 0; s < 8; ++s) wl4[s] = wlg[s * 256 + d];
#pragma unroll
      for (int s = 0; s < 8; ++s) wr4[s] = wrg[s * 256 + d];
#pragma unroll
      for (int s = 0; s < 8; ++s) ((float4*)WlS)[s * 256 + d] = wl4[s];
#pragma unroll
      for (int s = 0; s < 8; ++s) ((float4*)WrS)[s * 256 + d] = wr4[s];
    }
    __syncthreads();

#pragma unroll
    for (int h4l = 0; h4l < 8; ++h4l) {
      int h4 = c * 8 + h4l;          // global h-quad, ascending
      float4 e[4];
#pragma unroll
      for (int r = 0; r < 4; ++r) e[r] = ((const float4*)encS[r])[h4];
#pragma unroll
      for (int q = 0; q < 4; ++q) {
        int hh = h4l * 4 + q;        // row within chunk
        float wl = WlS[hh][d];
        float wr = WrS[hh][d];
#pragma unroll
        for (int r = 0; r < 4; ++r) {
          float ev = (q == 0) ? e[r].x : (q == 1) ? e[r].y : (q == 2) ? e[r].z : e[r].w;
          al[r] = fmaf(ev, wl, al[r]);
          ar[r] = fmaf(ev, wr, ar[r]);
        }
      }
    }
  }
#pragma unroll
  for (int r = 0; r < 4; ++r) {
    dl[(size_t)(r0 + r) * Dn + d] = al[r];
    dr[(size_t)(r0 + r) * Dn + d] = ar[r];
  }
}

// Grid 1024 = (b:16, iq:32, jseg:2); block = 4 i-rows x 64 j x 256 d.
// EXACT R0/R9 structure (tl=4, best measured 44us) with ONE change: pS row
// stride padded 16->17 floats. Old epilogue read pS[row][jl*16+k]: 64 lanes
// landed on 2 banks (32-way conflict x16 reads). 17 is coprime with 32 ->
// jl*17 mod 32 permutes, 2 lanes/bank = free. Writes <=2-way (free).
// Chunk-sum dp-ascending -> outputs bit-identical. Fused last-block finalize.
__global__ void pair_kernel(const float* __restrict__ dl,
                            const float* __restrict__ dr,
                            const float* __restrict__ U,
                            const float* __restrict__ bias,
                            float* __restrict__ out,
                            double* __restrict__ ws_acc) {
  int blk = blockIdx.x;          // b*64 + iq*2 + jseg
  int b = blk >> 6;              // 0..15
  int i0 = ((blk >> 1) & 31) * 4;
  int j0 = (blk & 1) * 64;
  int t = threadIdx.x;
  int dp = t & 15;
  int jj = t >> 4;

  __shared__ float dlS[4][Dn];        // 4 KB, cooperative coalesced stage
  __shared__ float pS[4][64 * 17];    // [row][jl*17 + dp], padded, 17 KB
  __shared__ float redS[8];

  // stage dl rows i0..i0+3 with one coalesced float4 load per thread
  ((float4*)dlS)[t] = ((const float4*)(dl + (size_t)(b * Ln + i0) * Dn))[t];

  float Ur[16];
  {
    const float4* U4 = (const float4*)(U + dp * 16);
#pragma unroll
    for (int q = 0; q < 4; ++q) {
      float4 u = U4[q];
      Ur[4*q+0] = u.x; Ur[4*q+1] = u.y; Ur[4*q+2] = u.z; Ur[4*q+3] = u.w;
    }
  }
  __syncthreads();

  float dlr[4][16];
#pragma unroll
  for (int r = 0; r < 4; ++r) {
#pragma unroll
    for (int q = 0; q < 4; ++q) {
      float4 a = *(const float4*)&dlS[r][dp * 16 + q * 4];
      dlr[r][4*q+0] = a.x; dlr[r][4*q+1] = a.y; dlr[r][4*q+2] = a.z; dlr[r][4*q+3] = a.w;
    }
  }

  const float* drt = dr + (size_t)b * Ln * Dn + (size_t)(j0 + jj) * Dn + dp * 16;
#pragma unroll
  for (int tl = 0; tl < 4; ++tl) {
    const float4* drp = (const float4*)(drt + (size_t)tl * 16 * Dn);
    float a0 = 0.f, a1 = 0.f, a2 = 0.f, a3 = 0.f;
#pragma unroll
    for (int q = 0; q < 4; ++q) {
      float4 v = drp[q];
#pragma unroll
      for (int c = 0; c < 4; ++c) {
        float dv = (c == 0) ? v.x : (c == 1) ? v.y : (c == 2) ? v.z : v.w;
        float uv = Ur[4*q+c];
        a0 = fmaf(fast_tanh(dlr[0][4*q+c] + dv), uv, a0);
        a1 = fmaf(fast_tanh(dlr[1][4*q+c] + dv), uv, a1);
        a2 = fmaf(fast_tanh(dlr[2][4*q+c] + dv), uv, a2);
        a3 = fmaf(fast_tanh(dlr[3][4*q+c] + dv), uv, a3);
      }
    }
    int sa = (tl * 16 + jj) * 17 + dp;   // jl*17 + dp, jl = tl*16+jj
    pS[0][sa] = a0; pS[1][sa] = a1; pS[2][sa] = a2; pS[3][sa] = a3;
  }
  __syncthreads();

  // epilogue: 256 outputs (4 rows x 64 j); thread t -> row = t>>6, jl = t&63
  int row = t >> 6;
  int jl = t & 63;
  int j = j0 + jl;
  const float* ps = &pS[row][jl * 17];
  float tot = 0.0f;
#pragma unroll
  for (int k = 0; k < 16; ++k) tot += ps[k];   // dp-ascending, same as R9
  int i = i0 + row;
  float l = tot + bias[0] - ((j == i) ? 1.0e8f : 0.0f);
  float e = __expf(-l);                       // l=-1e8 -> inf
  float p = __builtin_amdgcn_rcpf(1.0f + e);  // -> 0 on diagonal
  unsigned n = ((unsigned)(b * Ln + i) << 7) | (unsigned)j;
  unsigned bits = threefry_bits(0u, n);
  float u = __uint_as_float((bits >> 9) | 0x3f800000u) - 1.0f;
  float smp = (u < p) ? 1.0f : 0.0f;
  float sp_pos = softplus_f(l);
  float sp_neg = softplus_f(-l);
  float ent = p * sp_neg + (1.0f - p) * sp_pos;
  size_t idx = (size_t)(b * Ln + i) * Ln + j;
  out[OFF_MASK + idx] = l;
  out[OFF_SMP + idx] = smp;
  out[OFF_ENT + idx] = ent;
  atomicAdd(&out[OFF_GRAPH + i * Ln + j], smp * 0.0625f);
  float ent_v = ent;
  float lse_v = sp_pos - l * smp;

  // reduce over the 4 waves (all lanes valid)
#pragma unroll
  for (int off = 32; off > 0; off >>= 1) {
    ent_v += __shfl_down(ent_v, off);
    lse_v += __shfl_down(lse_v, off);
  }
  if ((t & 63) == 0) {
    redS[(t >> 6) * 2 + 0] = ent_v;
    redS[(t >> 6) * 2 + 1] = lse_v;
  }
  __syncthreads();
  if (t == 0) {
    float es = redS[0] + redS[2] + redS[4] + redS[6];
    float ls = redS[1] + redS[3] + redS[5] + redS[7];
    atomicAdd(&ws_acc[b], (double)es);
    atomicAdd(&ws_acc[16], (double)ls);
    __threadfence();   // make this block's ws atomics visible before counter
    unsigned int* ctr = (unsigned int*)&ws_acc[17];
    unsigned done = atomicAdd(ctr, 1u);
    if (done == (unsigned)(gridDim.x - 1)) {
      // fused finalize: all blocks' device-scope atomics are complete.
      // atomicAdd(,0.0) = L2-coherent read (bypasses potentially stale L1).
      double ls_tot = atomicAdd(&ws_acc[16], 0.0);
      out[OFF_LSE] = (float)(ls_tot / (double)(Bn * Ln * Ln));
      for (int q = 0; q < Bn; ++q) {
        double ev = atomicAdd(&ws_acc[q], 0.0);
        out[OFF_EREG + q] = (float)(ev / (double)(Ln * Ln));
      }
    }
  }
}

extern "C" void kernel_launch(void* const* d_in, const int* in_sizes, int n_in,
                              void* d_out, int out_size, void* d_ws, size_t ws_size,
                              hipStream_t stream) {
  const float* enc = (const float*)d_in[0];
  const float* Wl = (const float*)d_in[1];
  const float* Wr = (const float*)d_in[2];
  const float* U = (const float*)d_in[3];
  const float* bias = (const float*)d_in[4];
  float* out = (float*)d_out;

  // ws layout: dl (2048*256 f32), dr (2048*256 f32), 17 dbl acc + counter
  float* dl = (float*)d_ws;
  float* dr = dl + (size_t)Bn * Ln * Dn;
  double* ws_acc = (double*)(dr + (size_t)Bn * Ln * Dn);

  proj_kernel<<<Bn * Ln / 4, 256, 0, stream>>>(enc, Wl, Wr, dl, dr, out, ws_acc);
  pair_kernel<<<Bn * Ln / 2, 256, 0, stream>>>(dl, dr, U, bias, out, ws_acc);
}

// Round 3
// 123.234 us; speedup vs baseline: 3.8812x; 3.8812x over previous
//
#include <hip/hip_runtime.h>

#define Bn 16
#define Ln 128
#define Hn 256
#define Dn 256

// Output layout (flat fp32 concat, reference return order)
#define OFF_MASK   0          // (B,L,L) 262144
#define OFF_SMP    262144     // (B,L,L) 262144
#define OFF_ENT    524288     // (B,L,L) 262144
#define OFF_GRAPH  786432     // (L,L)   16384
#define OFF_LSE    802816     // scalar
#define OFF_EREG   802817     // (B,)    16

static __device__ __forceinline__ unsigned rotl32(unsigned x, int r) {
  return (x << r) | (x >> (32 - r));
}

// Threefry-2x32, 20 rounds, key = (0,1)  [jax.random.key(1)], partitionable
// random-bits path: counter = (hi=0, lo=flat_index), output = y0 ^ y1.
static __device__ __forceinline__ unsigned threefry_bits(unsigned c_hi, unsigned c_lo) {
  const unsigned ks0 = 0u, ks1 = 1u;
  const unsigned ks2 = 0u ^ 1u ^ 0x1BD11BDAu;
  unsigned x0 = c_hi + ks0;
  unsigned x1 = c_lo + ks1;
  x0 += x1; x1 = rotl32(x1, 13); x1 ^= x0;
  x0 += x1; x1 = rotl32(x1, 15); x1 ^= x0;
  x0 += x1; x1 = rotl32(x1, 26); x1 ^= x0;
  x0 += x1; x1 = rotl32(x1, 6);  x1 ^= x0;
  x0 += ks1; x1 += ks2 + 1u;
  x0 += x1; x1 = rotl32(x1, 17); x1 ^= x0;
  x0 += x1; x1 = rotl32(x1, 29); x1 ^= x0;
  x0 += x1; x1 = rotl32(x1, 16); x1 ^= x0;
  x0 += x1; x1 = rotl32(x1, 24); x1 ^= x0;
  x0 += ks2; x1 += ks0 + 2u;
  x0 += x1; x1 = rotl32(x1, 13); x1 ^= x0;
  x0 += x1; x1 = rotl32(x1, 15); x1 ^= x0;
  x0 += x1; x1 = rotl32(x1, 26); x1 ^= x0;
  x0 += x1; x1 = rotl32(x1, 6);  x1 ^= x0;
  x0 += ks0; x1 += ks1 + 3u;
  x0 += x1; x1 = rotl32(x1, 17); x1 ^= x0;
  x0 += x1; x1 = rotl32(x1, 29); x1 ^= x0;
  x0 += x1; x1 = rotl32(x1, 16); x1 ^= x0;
  x0 += x1; x1 = rotl32(x1, 24); x1 ^= x0;
  x0 += ks1; x1 += ks2 + 4u;
  x0 += x1; x1 = rotl32(x1, 13); x1 ^= x0;
  x0 += x1; x1 = rotl32(x1, 15); x1 ^= x0;
  x0 += x1; x1 = rotl32(x1, 26); x1 ^= x0;
  x0 += x1; x1 = rotl32(x1, 6);  x1 ^= x0;
  x0 += ks2; x1 += ks0 + 5u;
  return x0 ^ x1;
}

static __device__ __forceinline__ float softplus_f(float x) {
  // max(x,0) + log1p(exp(-|x|)); exact at |x|=1e8 (exp(-1e8)=0)
  return fmaxf(x, 0.0f) + log1pf(__expf(-fabsf(x)));
}

static __device__ __forceinline__ float fast_tanh(float x) {
  // tanh(x) = 2/(1+e^{-2x}) - 1; saturates correctly for |x| large
  float e = __expf(-2.0f * x);
  float r = __builtin_amdgcn_rcpf(1.0f + e);
  return fmaf(2.0f, r, -1.0f);
}

// Direct global->LDS DMA, 16B per lane, no VGPR round trip (R2's reg-staging
// spilled at the default 64-VGPR budget: 641MB scratch writes. This cannot
// spill.) LDS dest must be linear in lane order -- it is (index s*256+d).
static __device__ __forceinline__ void load_lds16(const float4* g, float4* l) {
  __builtin_amdgcn_global_load_lds((const __attribute__((address_space(1))) void*)g,
                                   (__attribute__((address_space(3))) void*)l,
                                   16, 0, 0);
}

// fp32 projections, 4 rows per block (512 blocks = 2/CU), LDS-staged enc AND
// LDS-staged Wl/Wr (8 chunks of 32 h-rows) via global_load_lds (async DMA).
// Compute order per (row,d) output is the SAME h-ascending fma chain ->
// dl/dr bit-identical. LDS = 68KB -> 2 blocks/CU (= old grid-limited occ).
__global__ void proj_kernel(const float* __restrict__ enc,
                            const float* __restrict__ Wl,
                            const float* __restrict__ Wr,
                            float* __restrict__ dl,
                            float* __restrict__ dr,
                            float* __restrict__ out,
                            double* __restrict__ ws_acc) {
  int gid = blockIdx.x * blockDim.x + threadIdx.x;
  if (gid < Ln * Ln) out[OFF_GRAPH + gid] = 0.0f;
  if (gid < 18) ws_acc[gid] = 0.0;

  int r0 = blockIdx.x * 4;     // 512 blocks x 4 rows = 2048 rows
  int d = threadIdx.x;         // 0..255
  __shared__ float encS[4][Hn];     // 4 KB
  __shared__ float WlS[32][Dn];     // 32 KB (one 32-h chunk)
  __shared__ float WrS[32][Dn];     // 32 KB
  ((float4*)encS)[d] = ((const float4*)(enc + (size_t)r0 * Hn))[d];

  float al[4] = {0.f, 0.f, 0.f, 0.f};
  float ar[4] = {0.f, 0.f, 0.f, 0.f};

  for (int c = 0; c < 8; ++c) {
    // issue async stage of this chunk (c>0: previous chunk's readers are
    // already past the barrier at loop bottom)
    {
      const float4* wlg = (const float4*)(Wl + (size_t)c * 32 * Dn);
      const float4* wrg = (const float4*)(Wr + (size_t)c * 32 * Dn);
#pragma unroll
      for (int s = 0; s < 8; ++s) load_lds16(&wlg[s * 256 + d], &((float4*)WlS)[s * 256 + d]);
#pragma unroll
      for (int s = 0; s < 8; ++s) load_lds16(&wrg[s * 256 + d], &((float4*)WrS)[s * 256 + d]);
    }
    // barrier implies s_waitcnt vmcnt(0): DMA complete (also orders encS @c=0)
    __syncthreads();

#pragma unroll
    for (int h4l = 0; h4l < 8; ++h4l) {
      float4 e[4];
#pragma unroll
      for (int r = 0; r < 4; ++r) e[r] = ((const float4*)encS[r])[c * 8 + h4l];
#pragma unroll
      for (int q = 0; q < 4; ++q) {
        int hh = h4l * 4 + q;        // row within chunk
        float wl = WlS[hh][d];
        float wr = WrS[hh][d];
#pragma unroll
        for (int r = 0; r < 4; ++r) {
          float ev = (q == 0) ? e[r].x : (q == 1) ? e[r].y : (q == 2) ? e[r].z : e[r].w;
          al[r] = fmaf(ev, wl, al[r]);
          ar[r] = fmaf(ev, wr, ar[r]);
        }
      }
    }
    if (c < 7) __syncthreads();   // readers done before next chunk's DMA lands
  }
#pragma unroll
  for (int r = 0; r < 4; ++r) {
    dl[(size_t)(r0 + r) * Dn + d] = al[r];
    dr[(size_t)(r0 + r) * Dn + d] = ar[r];
  }
}

// Grid 1024 = (b:16, iq:32, jseg:2); block = 4 i-rows x 64 j x 256 d.
// EXACT R0/R9 structure (tl=4) with pS row stride padded 16->17 floats
// (epilogue column read was a 32-way bank conflict at stride 16).
// Chunk-sum dp-ascending -> outputs bit-identical. Fused last-block finalize.
__global__ void pair_kernel(const float* __restrict__ dl,
                            const float* __restrict__ dr,
                            const float* __restrict__ U,
                            const float* __restrict__ bias,
                            float* __restrict__ out,
                            double* __restrict__ ws_acc) {
  int blk = blockIdx.x;          // b*64 + iq*2 + jseg
  int b = blk >> 6;              // 0..15
  int i0 = ((blk >> 1) & 31) * 4;
  int j0 = (blk & 1) * 64;
  int t = threadIdx.x;
  int dp = t & 15;
  int jj = t >> 4;

  __shared__ float dlS[4][Dn];        // 4 KB, cooperative coalesced stage
  __shared__ float pS[4][64 * 17];    // [row][jl*17 + dp], padded, 17 KB
  __shared__ float redS[8];

  // stage dl rows i0..i0+3 with one coalesced float4 load per thread
  ((float4*)dlS)[t] = ((const float4*)(dl + (size_t)(b * Ln + i0) * Dn))[t];

  float Ur[16];
  {
    const float4* U4 = (const float4*)(U + dp * 16);
#pragma unroll
    for (int q = 0; q < 4; ++q) {
      float4 u = U4[q];
      Ur[4*q+0] = u.x; Ur[4*q+1] = u.y; Ur[4*q+2] = u.z; Ur[4*q+3] = u.w;
    }
  }
  __syncthreads();

  float dlr[4][16];
#pragma unroll
  for (int r = 0; r < 4; ++r) {
#pragma unroll
    for (int q = 0; q < 4; ++q) {
      float4 a = *(const float4*)&dlS[r][dp * 16 + q * 4];
      dlr[r][4*q+0] = a.x; dlr[r][4*q+1] = a.y; dlr[r][4*q+2] = a.z; dlr[r][4*q+3] = a.w;
    }
  }

  const float* drt = dr + (size_t)b * Ln * Dn + (size_t)(j0 + jj) * Dn + dp * 16;
#pragma unroll
  for (int tl = 0; tl < 4; ++tl) {
    const float4* drp = (const float4*)(drt + (size_t)tl * 16 * Dn);
    float a0 = 0.f, a1 = 0.f, a2 = 0.f, a3 = 0.f;
#pragma unroll
    for (int q = 0; q < 4; ++q) {
      float4 v = drp[q];
#pragma unroll
      for (int c = 0; c < 4; ++c) {
        float dv = (c == 0) ? v.x : (c == 1) ? v.y : (c == 2) ? v.z : v.w;
        float uv = Ur[4*q+c];
        a0 = fmaf(fast_tanh(dlr[0][4*q+c] + dv), uv, a0);
        a1 = fmaf(fast_tanh(dlr[1][4*q+c] + dv), uv, a1);
        a2 = fmaf(fast_tanh(dlr[2][4*q+c] + dv), uv, a2);
        a3 = fmaf(fast_tanh(dlr[3][4*q+c] + dv), uv, a3);
      }
    }
    int sa = (tl * 16 + jj) * 17 + dp;   // jl*17 + dp, jl = tl*16+jj
    pS[0][sa] = a0; pS[1][sa] = a1; pS[2][sa] = a2; pS[3][sa] = a3;
  }
  __syncthreads();

  // epilogue: 256 outputs (4 rows x 64 j); thread t -> row = t>>6, jl = t&63
  int row = t >> 6;
  int jl = t & 63;
  int j = j0 + jl;
  const float* ps = &pS[row][jl * 17];
  float tot = 0.0f;
#pragma unroll
  for (int k = 0; k < 16; ++k) tot += ps[k];   // dp-ascending, same as R9
  int i = i0 + row;
  float l = tot + bias[0] - ((j == i) ? 1.0e8f : 0.0f);
  float e = __expf(-l);                       // l=-1e8 -> inf
  float p = __builtin_amdgcn_rcpf(1.0f + e);  // -> 0 on diagonal
  unsigned n = ((unsigned)(b * Ln + i) << 7) | (unsigned)j;
  unsigned bits = threefry_bits(0u, n);
  float u = __uint_as_float((bits >> 9) | 0x3f800000u) - 1.0f;
  float smp = (u < p) ? 1.0f : 0.0f;
  float sp_pos = softplus_f(l);
  float sp_neg = softplus_f(-l);
  float ent = p * sp_neg + (1.0f - p) * sp_pos;
  size_t idx = (size_t)(b * Ln + i) * Ln + j;
  out[OFF_MASK + idx] = l;
  out[OFF_SMP + idx] = smp;
  out[OFF_ENT + idx] = ent;
  atomicAdd(&out[OFF_GRAPH + i * Ln + j], smp * 0.0625f);
  float ent_v = ent;
  float lse_v = sp_pos - l * smp;

  // reduce over the 4 waves (all lanes valid)
#pragma unroll
  for (int off = 32; off > 0; off >>= 1) {
    ent_v += __shfl_down(ent_v, off);
    lse_v += __shfl_down(lse_v, off);
  }
  if ((t & 63) == 0) {
    redS[(t >> 6) * 2 + 0] = ent_v;
    redS[(t >> 6) * 2 + 1] = lse_v;
  }
  __syncthreads();
  if (t == 0) {
    float es = redS[0] + redS[2] + redS[4] + redS[6];
    float ls = redS[1] + redS[3] + redS[5] + redS[7];
    atomicAdd(&ws_acc[b], (double)es);
    atomicAdd(&ws_acc[16], (double)ls);
    __threadfence();   // make this block's ws atomics visible before counter
    unsigned int* ctr = (unsigned int*)&ws_acc[17];
    unsigned done = atomicAdd(ctr, 1u);
    if (done == (unsigned)(gridDim.x - 1)) {
      // fused finalize: all blocks' device-scope atomics are complete.
      // atomicAdd(,0.0) = L2-coherent read (bypasses potentially stale L1).
      double ls_tot = atomicAdd(&ws_acc[16], 0.0);
      out[OFF_LSE] = (float)(ls_tot / (double)(Bn * Ln * Ln));
      for (int q = 0; q < Bn; ++q) {
        double ev = atomicAdd(&ws_acc[q], 0.0);
        out[OFF_EREG + q] = (float)(ev / (double)(Ln * Ln));
      }
    }
  }
}

extern "C" void kernel_launch(void* const* d_in, const int* in_sizes, int n_in,
                              void* d_out, int out_size, void* d_ws, size_t ws_size,
                              hipStream_t stream) {
  const float* enc = (const float*)d_in[0];
  const float* Wl = (const float*)d_in[1];
  const float* Wr = (const float*)d_in[2];
  const float* U = (const float*)d_in[3];
  const float* bias = (const float*)d_in[4];
  float* out = (float*)d_out;

  // ws layout: dl (2048*256 f32), dr (2048*256 f32), 17 dbl acc + counter
  float* dl = (float*)d_ws;
  float* dr = dl + (size_t)Bn * Ln * Dn;
  double* ws_acc = (double*)(dr + (size_t)Bn * Ln * Dn);

  proj_kernel<<<Bn * Ln / 4, 256, 0, stream>>>(enc, Wl, Wr, dl, dr, out, ws_acc);
  pair_kernel<<<Bn * Ln / 2, 256, 0, stream>>>(dl, dr, U, bias, out, ws_acc);
}